// Round 2
// baseline (737.091 us; speedup 1.0000x reference)
//
#include <hip/hip_runtime.h>

typedef _Float16 f16;
typedef __attribute__((ext_vector_type(8))) _Float16 f16x8;
typedef __attribute__((ext_vector_type(4))) _Float16 f16x4;
typedef __attribute__((ext_vector_type(4))) float f32x4;

// ws layout (f16 elements)
#define WS_W1T 0                       // [512][128]
#define WS_W2T 65536                   // [512][512]
#define WS_W3T (65536 + 262144)        // [256][512], rows 251..255 zero

// ---------------------------------------------------------------------------
// Prologue: convert + transpose weights to f16, K-contiguous rows (W^T[n][k])
// ---------------------------------------------------------------------------
__global__ __launch_bounds__(256) void convert_weights_k(
    const float* __restrict__ W1, const float* __restrict__ W2,
    const float* __restrict__ W3, f16* __restrict__ ws)
{
  int idx = blockIdx.x * 256 + threadIdx.x;
  if (idx < 65536) {                       // W1T[n][k] = W1[k][n], n<512,k<128
    int n = idx >> 7, k = idx & 127;
    ws[WS_W1T + idx] = (f16)W1[k * 512 + n];
  } else if (idx < 327680) {               // W2T[n][k] = W2[k][n], 512x512
    int i = idx - 65536;
    int n = i >> 9, k = i & 511;
    ws[WS_W2T + i] = (f16)W2[k * 512 + n];
  } else if (idx < 458752) {               // W3T[n][k] = W3[k][n], n<251 else 0
    int i = idx - 327680;
    int n = i >> 9, k = i & 511;
    ws[WS_W3T + i] = (n < 251) ? (f16)W3[k * 251 + n] : (f16)(0.0f);
  }
}

// Swizzled LDS vector read: 16B at row m, byte offset kb (16B aligned)
__device__ __forceinline__ f16x8 lds_ld8(const char* base, int m, int strideB, int kb) {
  return *(const f16x8*)(base + m * strideB + (kb ^ ((m & 7) << 4)));
}

// ---------------------------------------------------------------------------
// One GEMM stage over a 32-row LDS tile. Wave owns NT*16 output cols at nb0.
// All 2*NT accumulators live; per-ks: 2 ds_read_b128 + NT global W loads +
// 2*NT independent MFMAs (software-pipelineable).
// dst rows are 1024B, XOR-swizzled by (m&7)<<4.
// ---------------------------------------------------------------------------
template<int KSTEPS, int NT, bool STORE_F16>
__device__ __forceinline__ void gemm_stage(
    const f16* __restrict__ WT, int ldw, int nb0,
    const char* __restrict__ src, int srcStride,
    char* __restrict__ dst, const float* __restrict__ bias,
    int l15, int lh)
{
  f32x4 acc[2][NT];
  #pragma unroll
  for (int h = 0; h < 2; ++h)
    #pragma unroll
    for (int nt = 0; nt < NT; ++nt) acc[h][nt] = f32x4{0.f, 0.f, 0.f, 0.f};

  const f16* wbase = WT + (nb0 + l15) * ldw + lh * 8;
  #pragma unroll
  for (int ks = 0; ks < KSTEPS; ++ks) {
    int kb = ks * 64 + lh * 16;
    f16x8 b0 = lds_ld8(src, l15, srcStride, kb);
    f16x8 b1 = lds_ld8(src, 16 + l15, srcStride, kb);
    f16x8 a[NT];
    #pragma unroll
    for (int nt = 0; nt < NT; ++nt)
      a[nt] = *(const f16x8*)(wbase + nt * 16 * ldw + ks * 32);
    #pragma unroll
    for (int nt = 0; nt < NT; ++nt) {
      acc[0][nt] = __builtin_amdgcn_mfma_f32_16x16x32_f16(a[nt], b0, acc[0][nt], 0, 0, 0);
      acc[1][nt] = __builtin_amdgcn_mfma_f32_16x16x32_f16(a[nt], b1, acc[1][nt], 0, 0, 0);
    }
  }
  #pragma unroll
  for (int nt = 0; nt < NT; ++nt) {
    int ncol = nb0 + nt * 16 + lh * 4;
    f32x4 bv;
    if (STORE_F16) bv = *(const f32x4*)(bias + ncol);
    #pragma unroll
    for (int h = 0; h < 2; ++h) {
      int m = h * 16 + l15;
      if (STORE_F16) {
        f16x4 hv;
        #pragma unroll
        for (int r = 0; r < 4; ++r) {
          float v = acc[h][nt][r] + bv[r];
          hv[r] = (f16)(v > 0.f ? v : 0.01f * v);
        }
        *(f16x4*)(dst + m * 1024 + ((ncol * 2) ^ ((m & 7) << 4))) = hv;
      } else {
        *(f32x4*)(dst + m * 1024 + ((ncol * 4) ^ ((m & 7) << 4))) = acc[h][nt];
      }
    }
  }
}

// ---------------------------------------------------------------------------
// Fused: x->MLP(f16 MFMA)->softmax->C51 projection. BM=32 rows, 8 waves.
// LDS rotation: xs(8K in A) -> h1(B) -> h2(A) -> logits(B) -> proj(A). 64 KB.
// ---------------------------------------------------------------------------
__global__ __launch_bounds__(512, 4) void fused_c51_k(
    const float* __restrict__ obs, const float* __restrict__ act,
    const float* __restrict__ rewards, const float* __restrict__ bootstrap,
    const float* __restrict__ discount, const float* __restrict__ q_support,
    const float* __restrict__ bias1, const float* __restrict__ bias2,
    const float* __restrict__ bias3, const f16* __restrict__ ws,
    float* __restrict__ out)
{
  extern __shared__ char smem[];
  char* bufA = smem;            // 32 KB
  char* bufB = smem + 32768;    // 32 KB

  const f16* W1T = ws + WS_W1T;
  const f16* W2T = ws + WS_W2T;
  const f16* W3T = ws + WS_W3T;

  const int tid = threadIdx.x;
  const int lane = tid & 63;
  const int w = tid >> 6;          // wave id 0..7
  const int l15 = lane & 15;
  const int lh = lane >> 4;        // 0..3
  const long rowBase = (long)blockIdx.x * 32;

  // ---- Phase A: stage x = concat(obs, act) as f16 into bufA (one granule/thread)
  {
    int m = tid >> 4, g = tid & 15;
    long row = rowBase + m;
    const float* src = (g < 12) ? (obs + row * 96 + g * 8)
                                : (act + row * 32 + (g - 12) * 8);
    float4 lo = ((const float4*)src)[0];
    float4 hi = ((const float4*)src)[1];
    f16x8 v;
    v[0] = (f16)lo.x; v[1] = (f16)lo.y; v[2] = (f16)lo.z; v[3] = (f16)lo.w;
    v[4] = (f16)hi.x; v[5] = (f16)hi.y; v[6] = (f16)hi.z; v[7] = (f16)hi.w;
    *(f16x8*)(bufA + m * 256 + ((g * 16) ^ ((m & 7) << 4))) = v;
  }
  __syncthreads();

  // ---- Stage 1: h1 = leaky(x @ W1 + b1).  A(xs,256B rows) -> B
  gemm_stage<4, 4, true>(W1T, 128, w * 64, bufA, 256, bufB, bias1, l15, lh);
  __syncthreads();

  // ---- Stage 2: h2 = leaky(h1 @ W2 + b2). B -> A
  gemm_stage<16, 4, true>(W2T, 512, w * 64, bufB, 1024, bufA, bias2, l15, lh);
  __syncthreads();

  // ---- Stage 3: logits = h2 @ W3 (b3 in epilogue). A -> B (f32)
  gemm_stage<16, 2, false>(W3T, 512, w * 32, bufA, 1024, bufB, nullptr, l15, lh);
  __syncthreads();

  // ---- Epilogue: softmax + C51 projection. Wave w owns rows w*4 .. w*4+3.
  {
    char* lg = bufB;
    float* pr = (float*)bufA;
    float zc[4], b3c[4];
    #pragma unroll
    for (int j = 0; j < 4; ++j) {
      int c = lane + j * 64;
      bool ok = c < 251;
      zc[j]  = ok ? q_support[c] : 0.f;
      b3c[j] = ok ? bias3[c] : 0.f;
    }
    // batch per-row scalars
    float rwv[4], bdv[4];
    #pragma unroll
    for (int i = 0; i < 4; ++i) {
      long row = rowBase + w * 4 + i;
      rwv[i] = rewards[row];
      bdv[i] = __fmul_rn(bootstrap[row], discount[row]);
    }
    #pragma unroll
    for (int i = 0; i < 4; ++i) {
      const int m = w * 4 + i;
      const long row = rowBase + m;
      #pragma unroll
      for (int j = 0; j < 4; ++j) pr[m * 256 + j * 64 + lane] = 0.f;
      float v[4];
      #pragma unroll
      for (int j = 0; j < 4; ++j) {
        int c = lane + j * 64;
        float t = *(const float*)(lg + m * 1024 + ((c * 4) ^ ((m & 7) << 4)));
        v[j] = (c < 251) ? t + b3c[j] : -3.0e38f;
      }
      float mx = fmaxf(fmaxf(v[0], v[1]), fmaxf(v[2], v[3]));
      #pragma unroll
      for (int s = 1; s < 64; s <<= 1) mx = fmaxf(mx, __shfl_xor(mx, s, 64));
      float e[4];
      float sum = 0.f;
      #pragma unroll
      for (int j = 0; j < 4; ++j) {
        int c = lane + j * 64;
        e[j] = (c < 251) ? __expf(v[j] - mx) : 0.f;
        sum += e[j];
      }
      #pragma unroll
      for (int s = 1; s < 64; s <<= 1) sum += __shfl_xor(sum, s, 64);
      float inv = 1.f / sum;
      #pragma unroll
      for (int j = 0; j < 4; ++j) {
        int c = lane + j * 64;
        if (c < 251) {
          float p = e[j] * inv;
          // exact replication of reference fp ops (no FMA contraction)
          float tz = __fadd_rn(rwv[i], __fmul_rn(bdv[i], zc[j]));
          tz = fminf(fmaxf(tz, -100.f), 100.f);
          float b = __fdiv_rn(__fadd_rn(tz, 100.f), 0.8f);
          float lf = floorf(b), uf = ceilf(b);
          int li = (int)lf, ui = (int)uf;
          bool eq = (li == ui);
          int li2 = li - ((eq && (ui > 0)) ? 1 : 0);
          int ui2 = ui + ((eq && (li < 250)) ? 1 : 0);
          atomicAdd(&pr[m * 256 + li2], p * ((float)ui2 - b));
          atomicAdd(&pr[m * 256 + ui2], p * (b - (float)li2));
        }
      }
      #pragma unroll
      for (int j = 0; j < 4; ++j) {
        int c = lane + j * 64;
        if (c < 251) out[row * 251 + c] = pr[m * 256 + c];
      }
    }
  }
}

extern "C" void kernel_launch(void* const* d_in, const int* in_sizes, int n_in,
                              void* d_out, int out_size, void* d_ws, size_t ws_size,
                              hipStream_t stream) {
  (void)n_in; (void)out_size; (void)ws_size;
  const float* obs       = (const float*)d_in[0];
  const float* actions   = (const float*)d_in[1];
  const float* rewards   = (const float*)d_in[2];
  const float* bootstrap = (const float*)d_in[3];
  const float* discount  = (const float*)d_in[4];
  const float* q_support = (const float*)d_in[5];
  const float* W1 = (const float*)d_in[6];
  const float* b1 = (const float*)d_in[7];
  const float* W2 = (const float*)d_in[8];
  const float* b2 = (const float*)d_in[9];
  const float* W3 = (const float*)d_in[10];
  const float* b3 = (const float*)d_in[11];
  float* out = (float*)d_out;
  f16* ws = (f16*)d_ws;
  const int B = in_sizes[2];

  hipLaunchKernelGGL(convert_weights_k, dim3(1792), dim3(256), 0, stream,
                     W1, W2, W3, ws);

  const int LDS_BYTES = 65536;  // 64 KB -> 2 blocks/CU
  hipFuncSetAttribute(reinterpret_cast<const void*>(fused_c51_k),
                      hipFuncAttributeMaxDynamicSharedMemorySize, LDS_BYTES);
  hipLaunchKernelGGL(fused_c51_k, dim3(B / 32), dim3(512), LDS_BYTES, stream,
                     obs, actions, rewards, bootstrap, discount, q_support,
                     b1, b2, b3, ws, out);
}

// Round 3
// 582.310 us; speedup vs baseline: 1.2658x; 1.2658x over previous
//
#include <hip/hip_runtime.h>
#include <stdint.h>

typedef _Float16 f16;
typedef __attribute__((ext_vector_type(8))) _Float16 f16x8;
typedef __attribute__((ext_vector_type(4))) _Float16 f16x4;
typedef __attribute__((ext_vector_type(4))) float f32x4;

// Tiled weight layout in ws (f16 elems), K-tile = 32:
// W1: 4  tiles of [512][32] @ WS_W1 (tile = 16384 elems = 32KB)
// W2: 16 tiles of [512][32] @ WS_W2
// W3: 16 tiles of [256][32] @ WS_W3 (n>=251 zeroed; tile = 8192 elems = 16KB)
#define WS_W1 0
#define WS_W2 65536
#define WS_W3 327680

__global__ __launch_bounds__(256) void convert_weights_k(
    const float* __restrict__ W1, const float* __restrict__ W2,
    const float* __restrict__ W3, f16* __restrict__ ws)
{
  int idx = blockIdx.x * 256 + threadIdx.x;
  if (idx < 65536) {
    int kt = idx >> 14, r = idx & 16383, n = r >> 5, kk = r & 31;
    ws[WS_W1 + idx] = (f16)W1[(kt * 32 + kk) * 512 + n];
  } else if (idx < 327680) {
    int i = idx - 65536;
    int kt = i >> 14, r = i & 16383, n = r >> 5, kk = r & 31;
    ws[WS_W2 + i] = (f16)W2[(kt * 32 + kk) * 512 + n];
  } else if (idx < 458752) {
    int i = idx - 327680;
    int kt = i >> 13, r = i & 8191, n = r >> 5, kk = r & 31;
    ws[WS_W3 + i] = (n < 251) ? (f16)W3[(kt * 32 + kk) * 251 + n] : (f16)0.0f;
  }
}

// async 16B/lane global->LDS (lds base must be wave-uniform; dest = base+lane*16)
__device__ __forceinline__ void gld16(char* lds, const char* g) {
  __builtin_amdgcn_global_load_lds(
      (const __attribute__((address_space(1))) uint32_t*)g,
      (__attribute__((address_space(3))) uint32_t*)lds, 16, 0, 0);
}

// Swizzled LDS vector read: 16B at row m, byte offset kb (16B aligned)
__device__ __forceinline__ f16x8 lds_ld8(const char* base, int m, int strideB, int kb) {
  return *(const f16x8*)(base + m * strideB + (kb ^ ((m & 7) << 4)));
}

#define CFENCE() asm volatile("" ::: "memory")
#define RAW_BARRIER() do { CFENCE(); __builtin_amdgcn_s_barrier(); CFENCE(); } while (0)

// ---------------------------------------------------------------------------
// One MLP layer over a 64-row activation tile in LDS.
// Weights double-buffer-staged tile-by-tile (K-tile=32) via global_load_lds;
// counted vmcnt keeps next tile's loads in flight across barriers.
// Wave w owns NT*16 output cols; acc[4][NT] stays in registers.
// ---------------------------------------------------------------------------
template<int KT, int ROUNDS, int NT>
__device__ __forceinline__ void mlp_stage(
    const f16* __restrict__ wsrc, char* wb0, char* wb1,
    const char* __restrict__ src, int srcStride,
    f32x4 acc[4][NT], int w, int lane, int l15, int lh)
{
  const int TILEB = ROUNDS * 8192;
  // issue tile 0
  {
    const char* gt = (const char*)wsrc;
    #pragma unroll
    for (int r = 0; r < ROUNDS; ++r) {
      int off = (r * 8 + w) * 1024;
      gld16(wb0 + off, gt + off + lane * 16);
    }
  }
  #pragma unroll
  for (int kt = 0; kt < KT; ++kt) {
    char* cur = (kt & 1) ? wb1 : wb0;
    if (kt + 1 < KT) {
      // A: all waves finished computing tile kt-1 -> other buffer is free
      asm volatile("s_waitcnt lgkmcnt(0)" ::: "memory");
      RAW_BARRIER();
      char* nxt = ((kt + 1) & 1) ? wb1 : wb0;
      const char* gt = (const char*)wsrc + (size_t)(kt + 1) * TILEB;
      #pragma unroll
      for (int r = 0; r < ROUNDS; ++r) {
        int off = (r * 8 + w) * 1024;
        gld16(nxt + off, gt + off + lane * 16);
      }
      if (ROUNDS == 4) asm volatile("s_waitcnt vmcnt(4)" ::: "memory");
      else             asm volatile("s_waitcnt vmcnt(2)" ::: "memory");
    } else {
      asm volatile("s_waitcnt vmcnt(0)" ::: "memory");
    }
    RAW_BARRIER();  // B: tile kt landed for every wave
    __builtin_amdgcn_sched_barrier(0);
    // compute tile kt: NT a-frags (weights, LDS linear [n][64B]) x 4 m-halves
    f16x8 a[NT];
    #pragma unroll
    for (int nt = 0; nt < NT; ++nt) {
      int n = w * (NT * 16) + nt * 16 + l15;
      a[nt] = *(const f16x8*)(cur + n * 64 + lh * 16);
    }
    #pragma unroll
    for (int mh = 0; mh < 4; ++mh) {
      f16x8 b = lds_ld8(src, mh * 16 + l15, srcStride, kt * 64 + lh * 16);
      #pragma unroll
      for (int nt = 0; nt < NT; ++nt)
        acc[mh][nt] = __builtin_amdgcn_mfma_f32_16x16x32_f16(a[nt], b, acc[mh][nt], 0, 0, 0);
    }
  }
}

// ---------------------------------------------------------------------------
// Fused kernel: BM=64 rows/block, 8 waves.
// LDS: h(64K) + x(16K) + Wdbuf(2x32K) = 144KB; proj reuses Wdbuf in epilogue.
// ---------------------------------------------------------------------------
__global__ __launch_bounds__(512, 2) void fused_c51_k(
    const float* __restrict__ obs, const float* __restrict__ act,
    const float* __restrict__ rewards, const float* __restrict__ bootstrap,
    const float* __restrict__ discount, const float* __restrict__ q_support,
    const float* __restrict__ bias1, const float* __restrict__ bias2,
    const float* __restrict__ bias3, const f16* __restrict__ ws,
    float* __restrict__ out)
{
  extern __shared__ char smem[];
  char* hbuf = smem;             // 64KB: [64 rows][1024B], swizzled
  char* xbuf = smem + 65536;     // 16KB: [64 rows][256B], swizzled
  char* wb0  = smem + 81920;     // 32KB weight tile buf 0
  char* wb1  = smem + 114688;    // 32KB weight tile buf 1
  float* pr  = (float*)(smem + 81920);  // 64KB projection (epilogue, over wb)

  const int tid = threadIdx.x;
  const int lane = tid & 63;
  const int w = tid >> 6;
  const int l15 = lane & 15;
  const int lh = lane >> 4;
  const long rowBase = (long)blockIdx.x * 64;

  // ---- stage x = concat(obs, act) as f16 into xbuf (2 granules of 8/thread)
  #pragma unroll
  for (int i = 0; i < 2; ++i) {
    int chunk = tid + i * 512;          // 0..1023
    int m = chunk >> 4, g = chunk & 15;
    long row = rowBase + m;
    const float* src = (g < 12) ? (obs + row * 96 + g * 8)
                                : (act + row * 32 + (g - 12) * 8);
    float4 lo = ((const float4*)src)[0];
    float4 hi = ((const float4*)src)[1];
    f16x8 v;
    v[0] = (f16)lo.x; v[1] = (f16)lo.y; v[2] = (f16)lo.z; v[3] = (f16)lo.w;
    v[4] = (f16)hi.x; v[5] = (f16)hi.y; v[6] = (f16)hi.z; v[7] = (f16)hi.w;
    *(f16x8*)(xbuf + m * 256 + ((g * 16) ^ ((m & 7) << 4))) = v;
  }
  __syncthreads();

  // ---- Stage 1: h1 = leaky(x @ W1 + b1)   (K=128 -> 4 tiles)
  {
    f32x4 acc[4][4];
    #pragma unroll
    for (int mh = 0; mh < 4; ++mh)
      #pragma unroll
      for (int nt = 0; nt < 4; ++nt) acc[mh][nt] = f32x4{0.f, 0.f, 0.f, 0.f};
    mlp_stage<4, 4, 4>(ws + WS_W1, wb0, wb1, xbuf, 256, acc, w, lane, l15, lh);
    // store h1 (f16, swizzled) — writes hbuf, no reader yet
    #pragma unroll
    for (int nt = 0; nt < 4; ++nt) {
      int ncol = w * 64 + nt * 16 + lh * 4;
      f32x4 bv = *(const f32x4*)(bias1 + ncol);
      #pragma unroll
      for (int mh = 0; mh < 4; ++mh) {
        int m = mh * 16 + l15;
        f16x4 hv;
        #pragma unroll
        for (int r = 0; r < 4; ++r) {
          float v = acc[mh][nt][r] + bv[r];
          hv[r] = (f16)(v > 0.f ? v : 0.01f * v);
        }
        *(f16x4*)(hbuf + m * 1024 + ((ncol * 2) ^ ((m & 7) << 4))) = hv;
      }
    }
  }
  __syncthreads();

  // ---- Stage 2: h2 = leaky(h1 @ W2 + b2) in regs  (K=512 -> 16 tiles)
  {
    f32x4 acc[4][4];
    #pragma unroll
    for (int mh = 0; mh < 4; ++mh)
      #pragma unroll
      for (int nt = 0; nt < 4; ++nt) acc[mh][nt] = f32x4{0.f, 0.f, 0.f, 0.f};
    mlp_stage<16, 4, 4>(ws + WS_W2, wb0, wb1, hbuf, 1024, acc, w, lane, l15, lh);
    __syncthreads();   // all waves done reading h1
    #pragma unroll
    for (int nt = 0; nt < 4; ++nt) {
      int ncol = w * 64 + nt * 16 + lh * 4;
      f32x4 bv = *(const f32x4*)(bias2 + ncol);
      #pragma unroll
      for (int mh = 0; mh < 4; ++mh) {
        int m = mh * 16 + l15;
        f16x4 hv;
        #pragma unroll
        for (int r = 0; r < 4; ++r) {
          float v = acc[mh][nt][r] + bv[r];
          hv[r] = (f16)(v > 0.f ? v : 0.01f * v);
        }
        *(f16x4*)(hbuf + m * 1024 + ((ncol * 2) ^ ((m & 7) << 4))) = hv;
      }
    }
  }
  __syncthreads();

  // ---- Stage 3: logits = h2 @ W3 in regs  (K=512 -> 16 tiles, N=256)
  {
    f32x4 acc[4][2];
    #pragma unroll
    for (int mh = 0; mh < 4; ++mh)
      #pragma unroll
      for (int nt = 0; nt < 2; ++nt) acc[mh][nt] = f32x4{0.f, 0.f, 0.f, 0.f};
    mlp_stage<16, 2, 2>(ws + WS_W3, wb0, wb1, hbuf, 1024, acc, w, lane, l15, lh);
    __syncthreads();   // all waves done reading h2
    #pragma unroll
    for (int nt = 0; nt < 2; ++nt) {
      int ncol = w * 32 + nt * 16 + lh * 4;
      #pragma unroll
      for (int mh = 0; mh < 4; ++mh) {
        int m = mh * 16 + l15;
        *(f32x4*)(hbuf + m * 1024 + ((ncol * 4) ^ ((m & 7) << 4))) = acc[mh][nt];
      }
    }
  }
  __syncthreads();

  // ---- Epilogue: softmax + C51 projection. Wave w owns rows w*8 .. w*8+7.
  {
    const char* lg = hbuf;
    float zc[4], b3c[4];
    #pragma unroll
    for (int j = 0; j < 4; ++j) {
      int c = lane + j * 64;
      bool ok = c < 251;
      zc[j]  = ok ? q_support[c] : 0.f;
      b3c[j] = ok ? bias3[c] : 0.f;
    }
    float rwv[8], bdv[8];
    #pragma unroll
    for (int i = 0; i < 8; ++i) {
      long row = rowBase + w * 8 + i;
      rwv[i] = rewards[row];
      bdv[i] = __fmul_rn(bootstrap[row], discount[row]);
    }
    #pragma unroll
    for (int i = 0; i < 8; ++i) {
      const int m = w * 8 + i;
      const long row = rowBase + m;
      #pragma unroll
      for (int j = 0; j < 4; ++j) pr[m * 256 + j * 64 + lane] = 0.f;
      float v[4];
      #pragma unroll
      for (int j = 0; j < 4; ++j) {
        int c = lane + j * 64;
        float t = *(const float*)(lg + m * 1024 + ((c * 4) ^ ((m & 7) << 4)));
        v[j] = (c < 251) ? t + b3c[j] : -3.0e38f;
      }
      float mx = fmaxf(fmaxf(v[0], v[1]), fmaxf(v[2], v[3]));
      #pragma unroll
      for (int s = 1; s < 64; s <<= 1) mx = fmaxf(mx, __shfl_xor(mx, s, 64));
      float e[4];
      float sum = 0.f;
      #pragma unroll
      for (int j = 0; j < 4; ++j) {
        int c = lane + j * 64;
        e[j] = (c < 251) ? __expf(v[j] - mx) : 0.f;
        sum += e[j];
      }
      #pragma unroll
      for (int s = 1; s < 64; s <<= 1) sum += __shfl_xor(sum, s, 64);
      float inv = 1.f / sum;
      #pragma unroll
      for (int j = 0; j < 4; ++j) {
        int c = lane + j * 64;
        if (c < 251) {
          float p = e[j] * inv;
          // exact replication of reference fp ops (no FMA contraction)
          float tz = __fadd_rn(rwv[i], __fmul_rn(bdv[i], zc[j]));
          tz = fminf(fmaxf(tz, -100.f), 100.f);
          float b = __fdiv_rn(__fadd_rn(tz, 100.f), 0.8f);
          float lf = floorf(b), uf = ceilf(b);
          int li = (int)lf, ui = (int)uf;
          bool eq = (li == ui);
          int li2 = li - ((eq && (ui > 0)) ? 1 : 0);
          int ui2 = ui + ((eq && (li < 250)) ? 1 : 0);
          atomicAdd(&pr[m * 256 + li2], p * ((float)ui2 - b));
          atomicAdd(&pr[m * 256 + ui2], p * (b - (float)li2));
        }
      }
      #pragma unroll
      for (int j = 0; j < 4; ++j) {
        int c = lane + j * 64;
        if (c < 251) out[row * 251 + c] = pr[m * 256 + c];
      }
    }
  }
}

extern "C" void kernel_launch(void* const* d_in, const int* in_sizes, int n_in,
                              void* d_out, int out_size, void* d_ws, size_t ws_size,
                              hipStream_t stream) {
  (void)n_in; (void)out_size; (void)ws_size;
  const float* obs       = (const float*)d_in[0];
  const float* actions   = (const float*)d_in[1];
  const float* rewards   = (const float*)d_in[2];
  const float* bootstrap = (const float*)d_in[3];
  const float* discount  = (const float*)d_in[4];
  const float* q_support = (const float*)d_in[5];
  const float* W1 = (const float*)d_in[6];
  const float* b1 = (const float*)d_in[7];
  const float* W2 = (const float*)d_in[8];
  const float* b2 = (const float*)d_in[9];
  const float* W3 = (const float*)d_in[10];
  const float* b3 = (const float*)d_in[11];
  float* out = (float*)d_out;
  f16* ws = (f16*)d_ws;
  const int B = in_sizes[2];

  hipLaunchKernelGGL(convert_weights_k, dim3(1792), dim3(256), 0, stream,
                     W1, W2, W3, ws);

  const int LDS_BYTES = 147456;  // 144 KB
  hipFuncSetAttribute(reinterpret_cast<const void*>(fused_c51_k),
                      hipFuncAttributeMaxDynamicSharedMemorySize, LDS_BYTES);
  hipLaunchKernelGGL(fused_c51_k, dim3(B / 64), dim3(512), LDS_BYTES, stream,
                     obs, actions, rewards, bootstrap, discount, q_support,
                     b1, b2, b3, ws, out);
}

// Round 4
// 573.214 us; speedup vs baseline: 1.2859x; 1.0159x over previous
//
#include <hip/hip_runtime.h>
#include <stdint.h>

typedef _Float16 f16;
typedef __attribute__((ext_vector_type(8))) _Float16 f16x8;
typedef __attribute__((ext_vector_type(4))) _Float16 f16x4;
typedef __attribute__((ext_vector_type(4))) float f32x4;

// Tiled weight layout in ws (f16 elems), K-tile = 32, tiles n-major [n][32]:
// W1: 4  tiles of [512][32] @ WS_W1 (tile = 32KB)
// W2: 16 tiles of [512][32] @ WS_W2 (tile = 32KB)
// W3: 16 tiles of [256][32] @ WS_W3 (n>=251 zeroed; tile = 16KB)
// Wave w's slice of each tile (its 16*NT output cols) is contiguous.
#define WS_W1 0
#define WS_W2 65536
#define WS_W3 327680

__global__ __launch_bounds__(256) void convert_weights_k(
    const float* __restrict__ W1, const float* __restrict__ W2,
    const float* __restrict__ W3, f16* __restrict__ ws)
{
  int idx = blockIdx.x * 256 + threadIdx.x;
  if (idx < 65536) {
    int kt = idx >> 14, r = idx & 16383, n = r >> 5, kk = r & 31;
    ws[WS_W1 + idx] = (f16)W1[(kt * 32 + kk) * 512 + n];
  } else if (idx < 327680) {
    int i = idx - 65536;
    int kt = i >> 14, r = i & 16383, n = r >> 5, kk = r & 31;
    ws[WS_W2 + i] = (f16)W2[(kt * 32 + kk) * 512 + n];
  } else if (idx < 458752) {
    int i = idx - 327680;
    int kt = i >> 13, r = i & 8191, n = r >> 5, kk = r & 31;
    ws[WS_W3 + i] = (n < 251) ? (f16)W3[(kt * 32 + kk) * 251 + n] : (f16)0.0f;
  }
}

// async 16B/lane global->LDS (lds base wave-uniform; dest = base+lane*16)
__device__ __forceinline__ void gld16(char* lds, const char* g) {
  __builtin_amdgcn_global_load_lds(
      (const __attribute__((address_space(1))) uint32_t*)g,
      (__attribute__((address_space(3))) uint32_t*)lds, 16, 0, 0);
}

// Swizzled LDS vector read: 16B at row m, byte offset kb (16B aligned)
__device__ __forceinline__ f16x8 lds_ld8(const char* base, int m, int strideB, int kb) {
  return *(const f16x8*)(base + m * strideB + (kb ^ ((m & 7) << 4)));
}

// ---------------------------------------------------------------------------
// One MLP layer over a 64-row activation tile in LDS.
// BARRIER-FREE: each wave streams its own contiguous NT*1024B weight slice
// per K-tile into its private double-buffered LDS slots via global_load_lds,
// waits with per-wave counted vmcnt, computes. Tight runtime loop (I$-small).
// ---------------------------------------------------------------------------
template<int NT>
__device__ __forceinline__ void mlp_stage(
    const f16* __restrict__ wsrc, int ktiles, int tileB,
    char* slot0, char* slot1,
    const char* __restrict__ src, int srcStride,
    f32x4 acc[4][NT], int w, int lane, int l15, int lh)
{
  const char* gsrc = (const char*)wsrc + w * (NT * 1024) + lane * 16;
  #pragma unroll
  for (int r = 0; r < NT; ++r) gld16(slot0 + r * 1024, gsrc + r * 1024);
  #pragma unroll 1
  for (int kt = 0; kt < ktiles; ++kt) {
    char* cur = (kt & 1) ? slot1 : slot0;
    char* nxt = (kt & 1) ? slot0 : slot1;
    if (kt + 1 < ktiles) {
      const char* g = gsrc + (size_t)(kt + 1) * tileB;
      __builtin_amdgcn_sched_barrier(0);
      #pragma unroll
      for (int r = 0; r < NT; ++r) gld16(nxt + r * 1024, g + r * 1024);
      asm volatile("s_waitcnt vmcnt(%0)" :: "n"(NT) : "memory");
    } else {
      asm volatile("s_waitcnt vmcnt(0)" ::: "memory");
    }
    __builtin_amdgcn_sched_barrier(0);
    f16x8 a[NT];
    #pragma unroll
    for (int nt = 0; nt < NT; ++nt)
      a[nt] = *(const f16x8*)(cur + (nt * 16 + l15) * 64 + lh * 16);
    __builtin_amdgcn_s_setprio(1);
    #pragma unroll
    for (int mh = 0; mh < 4; ++mh) {
      f16x8 b = lds_ld8(src, mh * 16 + l15, srcStride, kt * 64 + lh * 16);
      #pragma unroll
      for (int nt = 0; nt < NT; ++nt)
        acc[mh][nt] = __builtin_amdgcn_mfma_f32_16x16x32_f16(a[nt], b, acc[mh][nt], 0, 0, 0);
    }
    __builtin_amdgcn_s_setprio(0);
  }
}

// ---------------------------------------------------------------------------
// Fused kernel: BM=64 rows/block, 8 waves.
// LDS: h(64K) + x(16K) + per-wave weight dbuf slots (8w x 8K = 64K) = 144KB.
// Projection buffer reuses the weight-slot region in the epilogue.
// ---------------------------------------------------------------------------
__global__ __launch_bounds__(512, 2) void fused_c51_k(
    const float* __restrict__ obs, const float* __restrict__ act,
    const float* __restrict__ rewards, const float* __restrict__ bootstrap,
    const float* __restrict__ discount, const float* __restrict__ q_support,
    const float* __restrict__ bias1, const float* __restrict__ bias2,
    const float* __restrict__ bias3, const f16* __restrict__ ws,
    float* __restrict__ out)
{
  extern __shared__ char smem[];
  char* hbuf = smem;             // 64KB: [64 rows][1024B], swizzled
  char* xbuf = smem + 65536;     // 16KB: [64 rows][256B], swizzled
  char* wbase = smem + 81920;    // 64KB: wave w -> 8KB (two 4KB slots)

  const int tid = threadIdx.x;
  const int lane = tid & 63;
  const int w = tid >> 6;
  const int l15 = lane & 15;
  const int lh = lane >> 4;
  const long rowBase = (long)blockIdx.x * 64;
  char* slot0 = wbase + w * 8192;
  char* slot1 = slot0 + 4096;

  // ---- stage x = concat(obs, act) as f16 into xbuf (2 granules of 8/thread)
  #pragma unroll
  for (int i = 0; i < 2; ++i) {
    int chunk = tid + i * 512;          // 0..1023
    int m = chunk >> 4, g = chunk & 15;
    long row = rowBase + m;
    const float* src = (g < 12) ? (obs + row * 96 + g * 8)
                                : (act + row * 32 + (g - 12) * 8);
    float4 lo = ((const float4*)src)[0];
    float4 hi = ((const float4*)src)[1];
    f16x8 v;
    v[0] = (f16)lo.x; v[1] = (f16)lo.y; v[2] = (f16)lo.z; v[3] = (f16)lo.w;
    v[4] = (f16)hi.x; v[5] = (f16)hi.y; v[6] = (f16)hi.z; v[7] = (f16)hi.w;
    *(f16x8*)(xbuf + m * 256 + ((g * 16) ^ ((m & 7) << 4))) = v;
  }
  __syncthreads();

  // ---- Stage 1: h1 = leaky(x @ W1 + b1)   (K=128 -> 4 tiles)
  {
    f32x4 acc[4][4];
    #pragma unroll
    for (int mh = 0; mh < 4; ++mh)
      #pragma unroll
      for (int nt = 0; nt < 4; ++nt) acc[mh][nt] = f32x4{0.f, 0.f, 0.f, 0.f};
    mlp_stage<4>(ws + WS_W1, 4, 32768, slot0, slot1, xbuf, 256, acc, w, lane, l15, lh);
    #pragma unroll
    for (int nt = 0; nt < 4; ++nt) {
      int ncol = w * 64 + nt * 16 + lh * 4;
      f32x4 bv = *(const f32x4*)(bias1 + ncol);
      #pragma unroll
      for (int mh = 0; mh < 4; ++mh) {
        int m = mh * 16 + l15;
        f16x4 hv;
        #pragma unroll
        for (int r = 0; r < 4; ++r) {
          float v = acc[mh][nt][r] + bv[r];
          hv[r] = (f16)(v > 0.f ? v : 0.01f * v);
        }
        *(f16x4*)(hbuf + m * 1024 + ((ncol * 2) ^ ((m & 7) << 4))) = hv;
      }
    }
  }
  __syncthreads();

  // ---- Stage 2: h2 = leaky(h1 @ W2 + b2) in regs  (K=512 -> 16 tiles)
  {
    f32x4 acc[4][4];
    #pragma unroll
    for (int mh = 0; mh < 4; ++mh)
      #pragma unroll
      for (int nt = 0; nt < 4; ++nt) acc[mh][nt] = f32x4{0.f, 0.f, 0.f, 0.f};
    mlp_stage<4>(ws + WS_W2, 16, 32768, slot0, slot1, hbuf, 1024, acc, w, lane, l15, lh);
    __syncthreads();   // all waves done reading h1
    #pragma unroll
    for (int nt = 0; nt < 4; ++nt) {
      int ncol = w * 64 + nt * 16 + lh * 4;
      f32x4 bv = *(const f32x4*)(bias2 + ncol);
      #pragma unroll
      for (int mh = 0; mh < 4; ++mh) {
        int m = mh * 16 + l15;
        f16x4 hv;
        #pragma unroll
        for (int r = 0; r < 4; ++r) {
          float v = acc[mh][nt][r] + bv[r];
          hv[r] = (f16)(v > 0.f ? v : 0.01f * v);
        }
        *(f16x4*)(hbuf + m * 1024 + ((ncol * 2) ^ ((m & 7) << 4))) = hv;
      }
    }
  }
  __syncthreads();

  // ---- Stage 3: logits = h2 @ W3 in regs  (K=512 -> 16 tiles, N=256)
  {
    f32x4 acc[4][2];
    #pragma unroll
    for (int mh = 0; mh < 4; ++mh)
      #pragma unroll
      for (int nt = 0; nt < 2; ++nt) acc[mh][nt] = f32x4{0.f, 0.f, 0.f, 0.f};
    mlp_stage<2>(ws + WS_W3, 16, 16384, slot0, slot1, hbuf, 1024, acc, w, lane, l15, lh);
    __syncthreads();   // all waves done reading h2
    #pragma unroll
    for (int nt = 0; nt < 2; ++nt) {
      int ncol = w * 32 + nt * 16 + lh * 4;
      #pragma unroll
      for (int mh = 0; mh < 4; ++mh) {
        int m = mh * 16 + l15;
        *(f32x4*)(hbuf + m * 1024 + ((ncol * 4) ^ ((m & 7) << 4))) = acc[mh][nt];
      }
    }
  }
  __syncthreads();

  // ---- Epilogue: softmax + C51 projection. Wave w owns rows w*8 .. w*8+7.
  {
    const char* lg = hbuf;
    float* pr = (float*)wbase;   // 64KB; wave w's rows live in its own 8KB
    float zc[4], b3c[4];
    #pragma unroll
    for (int j = 0; j < 4; ++j) {
      int c = lane + j * 64;
      bool ok = c < 251;
      zc[j]  = ok ? q_support[c] : 0.f;
      b3c[j] = ok ? bias3[c] : 0.f;
    }
    #pragma unroll 1
    for (int i = 0; i < 8; ++i) {
      const int m = w * 8 + i;
      const long row = rowBase + m;
      float rw = rewards[row];
      float bd = __fmul_rn(bootstrap[row], discount[row]);
      #pragma unroll
      for (int j = 0; j < 4; ++j) pr[m * 256 + j * 64 + lane] = 0.f;
      float v[4];
      #pragma unroll
      for (int j = 0; j < 4; ++j) {
        int c = lane + j * 64;
        float t = *(const float*)(lg + m * 1024 + ((c * 4) ^ ((m & 7) << 4)));
        v[j] = (c < 251) ? t + b3c[j] : -3.0e38f;
      }
      float mx = fmaxf(fmaxf(v[0], v[1]), fmaxf(v[2], v[3]));
      #pragma unroll
      for (int s = 1; s < 64; s <<= 1) mx = fmaxf(mx, __shfl_xor(mx, s, 64));
      float e[4];
      float sum = 0.f;
      #pragma unroll
      for (int j = 0; j < 4; ++j) {
        int c = lane + j * 64;
        e[j] = (c < 251) ? __expf(v[j] - mx) : 0.f;
        sum += e[j];
      }
      #pragma unroll
      for (int s = 1; s < 64; s <<= 1) sum += __shfl_xor(sum, s, 64);
      float inv = 1.f / sum;
      #pragma unroll
      for (int j = 0; j < 4; ++j) {
        int c = lane + j * 64;
        if (c < 251) {
          float p = e[j] * inv;
          // exact replication of reference fp ops (no FMA contraction)
          float tz = __fadd_rn(rw, __fmul_rn(bd, zc[j]));
          tz = fminf(fmaxf(tz, -100.f), 100.f);
          float b = __fdiv_rn(__fadd_rn(tz, 100.f), 0.8f);
          float lf = floorf(b), uf = ceilf(b);
          int li = (int)lf, ui = (int)uf;
          bool eq = (li == ui);
          int li2 = li - ((eq && (ui > 0)) ? 1 : 0);
          int ui2 = ui + ((eq && (li < 250)) ? 1 : 0);
          atomicAdd(&pr[m * 256 + li2], p * ((float)ui2 - b));
          atomicAdd(&pr[m * 256 + ui2], p * (b - (float)li2));
        }
      }
      #pragma unroll
      for (int j = 0; j < 4; ++j) {
        int c = lane + j * 64;
        if (c < 251) out[row * 251 + c] = pr[m * 256 + c];
      }
    }
  }
}

extern "C" void kernel_launch(void* const* d_in, const int* in_sizes, int n_in,
                              void* d_out, int out_size, void* d_ws, size_t ws_size,
                              hipStream_t stream) {
  (void)n_in; (void)out_size; (void)ws_size;
  const float* obs       = (const float*)d_in[0];
  const float* actions   = (const float*)d_in[1];
  const float* rewards   = (const float*)d_in[2];
  const float* bootstrap = (const float*)d_in[3];
  const float* discount  = (const float*)d_in[4];
  const float* q_support = (const float*)d_in[5];
  const float* W1 = (const float*)d_in[6];
  const float* b1 = (const float*)d_in[7];
  const float* W2 = (const float*)d_in[8];
  const float* b2 = (const float*)d_in[9];
  const float* W3 = (const float*)d_in[10];
  const float* b3 = (const float*)d_in[11];
  float* out = (float*)d_out;
  f16* ws = (f16*)d_ws;
  const int B = in_sizes[2];

  hipLaunchKernelGGL(convert_weights_k, dim3(1792), dim3(256), 0, stream,
                     W1, W2, W3, ws);

  const int LDS_BYTES = 147456;  // 144 KB
  hipFuncSetAttribute(reinterpret_cast<const void*>(fused_c51_k),
                      hipFuncAttributeMaxDynamicSharedMemorySize, LDS_BYTES);
  hipLaunchKernelGGL(fused_c51_k, dim3(B / 64), dim3(512), LDS_BYTES, stream,
                     obs, actions, rewards, bootstrap, discount, q_support,
                     b1, b2, b3, ws, out);
}